// Round 9
// baseline (168.362 us; speedup 1.0000x reference)
//
#include <hip/hip_runtime.h>
#include <hip/hip_bf16.h>
#include <math.h>

// KoLeo loss: B=8, T=4096, D=256 fp32 input.
// Phase 1: convert x -> bf16 (ws)
// Phase 2: per-batch Gram X·X^T via bf16 MFMA, SYMMETRY-HALVED:
//          one block per upper-triangle 256x256 panel pair (rt <= ct);
//          row-keys updated from row-max, col-keys from col-max (transpose),
//          merged across blocks with atomicMax on (orderable-f32, ~idx) u64.
// Phase 3: bf16 distances (from xb, L2-hot) + log-mean loss.

#define Bq 8
#define Tq 4096
#define Dq 256
#define NPAIR 136                 // 16*17/2 upper-triangle panel pairs
#define TILE_BYTES (128 * 512)    // 64 KB: 128 s-cols x 512 B

typedef __attribute__((ext_vector_type(8))) short bf16x8;
typedef __attribute__((ext_vector_type(4))) float f32x4;
typedef unsigned int u32;
typedef unsigned long long u64;

__device__ __forceinline__ unsigned short f2bf(float f) {
    unsigned int u = __float_as_uint(f);
    unsigned int r = (u + 0x7fffu + ((u >> 16) & 1u)) >> 16;   // RNE
    return (unsigned short)r;
}

__device__ __forceinline__ void gload_lds16(const void* g, void* l) {
    typedef __attribute__((address_space(1))) const unsigned int gu32;
    typedef __attribute__((address_space(3))) unsigned int lu32;
    __builtin_amdgcn_global_load_lds((gu32*)g, (lu32*)l, 16, 0, 0);
}

__device__ __forceinline__ u64 packkey(float v, int ix) {
    const u32 u = __float_as_uint(v);
    const u32 o = (u & 0x80000000u) ? ~u : (u | 0x80000000u);   // orderable fp32
    return ((u64)o << 32) | (u32)(~ix);                         // ties: low idx wins
}

// ---------------- Phase 1: fp32 -> bf16 ----------------
__global__ void cvt_kernel(const float* __restrict__ x, unsigned short* __restrict__ xb) {
    int i = blockIdx.x * blockDim.x + threadIdx.x;  // one float4 per thread
    const int n4 = Bq * Tq * Dq / 4;
    if (i < n4) {
        float4 v = ((const float4*)x)[i];
        ushort4 o;
        o.x = f2bf(v.x); o.y = f2bf(v.y); o.z = f2bf(v.z); o.w = f2bf(v.w);
        ((ushort4*)xb)[i] = o;
    }
}

// ---------------- Phase 2: symmetric Gram + dual-sided argmax ----------------
// Grid: 1088 blocks = 8 batches x 136 pairs (batch = bid & 7 for XCD/L2 affinity).
// Block: 512 threads = 8 waves as 4M x 2N; afrag[8][4] = rt-panel rows in regs.
// ct-panel (256 cols) staged as 2 x 64 KB LDS tiles, both issued at prologue;
// counted vmcnt(8): tile1's 8 loads stay in flight under tile0 compute.
// Coverage: (t,s), tp=t>>8, sp=s>>8: tp<=sp -> row-pass of pair(tp,sp);
//           tp>sp -> col-pass of pair(sp,tp). Diag pairs: full square, row-pass
//           only (col-pass redundant). Diagonal t==s excluded via hasDiag guard.
// NOTE: launch_bounds must stay (512,2); (512,4) demotes afrag -> 870 MB FETCH (R4).
__global__ __launch_bounds__(512, 2)
void argmax_kernel(const unsigned short* __restrict__ xb, u64* __restrict__ keys) {
    const int bid   = blockIdx.x;
    const int batch = bid & 7;
    int pidx = bid >> 3;                   // 0..135
    int rt = 0;
    while (pidx >= 16 - rt) { pidx -= 16 - rt; ++rt; }
    const int ct = rt + pidx;              // ct >= rt
    const bool offDiag = (rt != ct);

    const int tid   = threadIdx.x;
    const int lane  = tid & 63;
    const int wave  = tid >> 6;            // 0..7
    const int waveM = wave >> 1;           // 0..3
    const int waveN = wave & 1;            // 0..1
    const int lrow  = lane & 15;           // A-row / B-col / C-col
    const int lk    = lane >> 4;           // k-group / C row-group

    const unsigned short* xB = xb + (size_t)batch * Tq * Dq;
    const char* xBb = (const char*)xB;                 // byte view, row stride 512 B
    const int rowPanel = rt * 256;
    const int colPanel = ct * 256;
    const int rowBase = rowPanel + waveM * 64;         // wave's 64 rows
    const int sW = waveN * 64;                         // wave's local col base

    __shared__ char smem[2 * TILE_BYTES];              // 128 KB, two col-tiles

    // ---- A fragments: afrag[kk][mi], loaded once (issued BEFORE staging so the
    //      counted vmcnt(8) below leaves exactly tile1's 8 loads in flight) ----
    bf16x8 afrag[8][4];
#pragma unroll
    for (int mi = 0; mi < 4; ++mi) {
        const unsigned short* rp = xB + (size_t)(rowBase + mi * 16 + lrow) * Dq + lk * 8;
#pragma unroll
        for (int kk = 0; kk < 8; ++kk)
            afrag[kk][mi] = *(const bf16x8*)(rp + kk * 32);
    }

    // ---- loop-invariant lane offsets (swizzle: byte q ^ ((s&7)<<4), rule #21) ----
    int g_off[8];                          // staging source offsets within a tile
#pragma unroll
    for (int it = 0; it < 8; ++it) {
        const int ls = it * 8192 + tid * 16;
        const int s_local = ls >> 9;
        const int q = ls & 511;
        g_off[it] = s_local * 512 + (q ^ ((s_local & 7) << 4));
    }
    int dsoff[8][2];                       // ds-read offsets, sub-phase 0
#pragma unroll
    for (int ni = 0; ni < 2; ++ni) {
        const int s_local = sW + ni * 16 + lrow;
#pragma unroll
        for (int kk = 0; kk < 8; ++kk)
            dsoff[kk][ni] = s_local * 512 + ((kk * 64 + lk * 16) ^ ((s_local & 7) << 4));
    }

    auto STAGE = [&](int tt, char* lbase) {            // stage 128-col tile tt
        const char* gsrc = xBb + (size_t)(colPanel + tt * 128) * 512;
#pragma unroll
        for (int it = 0; it < 8; ++it)
            gload_lds16(gsrc + g_off[it], lbase + it * 8192 + tid * 16);
    };

    float best[4][4];   // row-argmax accumulators [mi][j]
    int   bidxv[4][4];
#pragma unroll
    for (int mi = 0; mi < 4; ++mi)
#pragma unroll
        for (int j = 0; j < 4; ++j) { best[mi][j] = -1e30f; bidxv[mi][j] = 0; }

    float cv[2][2];     // col-argmax of current tile [p][ni]
    int   cix[2][2];

    // compute one 256x128 tile: MFMA + row updates + (offDiag) col reduce
    auto COMPUTE = [&](int tt, const char* lbase) {
        const int C0 = colPanel + tt * 128;
#pragma unroll
        for (int p = 0; p < 2; ++p) {      // two 32-col sub-phases per wave
            const int poff = p * (32 * 512);

            f32x4 acc[4][2];
#pragma unroll
            for (int mi = 0; mi < 4; ++mi)
#pragma unroll
                for (int ni = 0; ni < 2; ++ni)
                    acc[mi][ni] = (f32x4){0.f, 0.f, 0.f, 0.f};

#pragma unroll
            for (int kk = 0; kk < 8; ++kk) {
                bf16x8 b0 = *(const bf16x8*)(lbase + poff + dsoff[kk][0]);
                bf16x8 b1 = *(const bf16x8*)(lbase + poff + dsoff[kk][1]);
#pragma unroll
                for (int mi = 0; mi < 4; ++mi) {
                    acc[mi][0] = __builtin_amdgcn_mfma_f32_16x16x32_bf16(
                        afrag[kk][mi], b0, acc[mi][0], 0, 0, 0);
                    acc[mi][1] = __builtin_amdgcn_mfma_f32_16x16x32_bf16(
                        afrag[kk][mi], b1, acc[mi][1], 0, 0, 0);
                }
            }

            // ---- row-argmax update (diag hoisted to wave-uniform branch) ----
            const int colBase = C0 + sW + p * 32;
            const int s0v = colBase + lrow;
            const int s1v = colBase + 16 + lrow;
            const bool hasDiag = (colBase < rowBase + 64) && (rowBase < colBase + 32);
            if (hasDiag) {
#pragma unroll
                for (int mi = 0; mi < 4; ++mi) {
                    const int tbase = rowBase + mi * 16 + lk * 4;
#pragma unroll
                    for (int j = 0; j < 4; ++j) {
                        const int tj = tbase + j;
                        {
                            const float v = acc[mi][0][j];
                            const bool ok = (s0v != tj) && (v > best[mi][j]);
                            best[mi][j] = ok ? v : best[mi][j];
                            bidxv[mi][j] = ok ? s0v : bidxv[mi][j];
                        }
                        {
                            const float v = acc[mi][1][j];
                            const bool ok = (s1v != tj) && (v > best[mi][j]);
                            best[mi][j] = ok ? v : best[mi][j];
                            bidxv[mi][j] = ok ? s1v : bidxv[mi][j];
                        }
                    }
                }
            } else {
#pragma unroll
                for (int mi = 0; mi < 4; ++mi) {
#pragma unroll
                    for (int j = 0; j < 4; ++j) {
                        {
                            const float v = acc[mi][0][j];
                            const bool ok = (v > best[mi][j]);
                            best[mi][j] = ok ? v : best[mi][j];
                            bidxv[mi][j] = ok ? s0v : bidxv[mi][j];
                        }
                        {
                            const float v = acc[mi][1][j];
                            const bool ok = (v > best[mi][j]);
                            best[mi][j] = ok ? v : best[mi][j];
                            bidxv[mi][j] = ok ? s1v : bidxv[mi][j];
                        }
                    }
                }
            }

            // ---- col-argmax reduce (symmetry pass; skipped for diag pairs) ----
            if (offDiag) {
#pragma unroll
                for (int ni = 0; ni < 2; ++ni) {
                    float cm = -1e30f; int ci = 0;
#pragma unroll
                    for (int mi = 0; mi < 4; ++mi) {
                        const int rb = rowBase + mi * 16 + lk * 4;
#pragma unroll
                        for (int j = 0; j < 4; ++j) {
                            const float v = acc[mi][ni][j];
                            const bool ok = (v > cm);   // rows ascend -> first max
                            cm = ok ? v : cm;
                            ci = ok ? (rb + j) : ci;
                        }
                    }
#pragma unroll
                    for (int m = 16; m <= 32; m <<= 1) {   // reduce over lk lanes
                        float ov = __shfl_xor(cm, m, 64);
                        int   oi = __shfl_xor(ci, m, 64);
                        if (ov > cm || (ov == cm && oi < ci)) { cm = ov; ci = oi; }
                    }
                    cv[p][ni] = cm; cix[p][ni] = ci;
                }
            }
        }
    };

    auto FLUSH_COL = [&](int tt) {         // issue col atomics (lanes 0..15)
        if (offDiag && lane < 16) {
            const int C0 = colPanel + tt * 128 + sW;
#pragma unroll
            for (int p = 0; p < 2; ++p)
#pragma unroll
                for (int ni = 0; ni < 2; ++ni) {
                    const int col = C0 + p * 32 + ni * 16 + lane;
                    atomicMax(keys + batch * Tq + col, packkey(cv[p][ni], cix[p][ni]));
                }
        }
    };

    // ---- prologue: stage both col-tiles; tile1 flies under tile0 compute ----
    STAGE(0, smem);
    STAGE(1, smem + TILE_BYTES);
    asm volatile("s_waitcnt vmcnt(8)" ::: "memory");   // afrag + tile0 done
    __builtin_amdgcn_s_barrier();
    __builtin_amdgcn_sched_barrier(0);

    COMPUTE(0, smem);

    asm volatile("s_waitcnt vmcnt(0)" ::: "memory");   // tile1 staged
    __builtin_amdgcn_s_barrier();
    __builtin_amdgcn_sched_barrier(0);

    FLUSH_COL(0);                                      // atomics hide under tile1
    COMPUTE(1, smem + TILE_BYTES);
    FLUSH_COL(1);

    // ---- row-side: reduce across the 16 lanes sharing each C-row, atomic ----
#pragma unroll
    for (int mi = 0; mi < 4; ++mi) {
#pragma unroll
        for (int j = 0; j < 4; ++j) {
            float v = best[mi][j];
            int   ix = bidxv[mi][j];
#pragma unroll
            for (int m = 8; m >= 1; m >>= 1) {
                float ov = __shfl_xor(v, m, 64);
                int   oi = __shfl_xor(ix, m, 64);
                if (ov > v || (ov == v && oi < ix)) { v = ov; ix = oi; }
            }
            if (lrow == 0) {
                const int row = rowBase + mi * 16 + lk * 4 + j;
                atomicMax(keys + batch * Tq + row, packkey(v, ix));
            }
        }
    }
}

// ---------------- Phase 3: bf16 distance + loss ----------------
__global__ void loss_kernel(const unsigned short* __restrict__ xb,
                            const u64* __restrict__ keys, float* __restrict__ out) {
    const int lane = threadIdx.x & 63;
    const int wave = threadIdx.x >> 6;          // 4 waves / block
    const int gw = blockIdx.x * 4 + wave;       // 2048 global waves
    float lsum = 0.f;

    for (int row = gw; row < Bq * Tq; row += 2048) {
        const int b = row >> 12;
        const int t = row & (Tq - 1);
        const int s = (int)((u32)(~keys[row]));
        const ushort4* xt = (const ushort4*)(xb + ((size_t)b * Tq + t) * Dq);
        const ushort4* xs = (const ushort4*)(xb + ((size_t)b * Tq + s) * Dq);
        ushort4 a = xt[lane];                   // 4 bf16 per lane, 64 lanes = 256
        ushort4 c = xs[lane];
        float ax = __uint_as_float((u32)a.x << 16), cx = __uint_as_float((u32)c.x << 16);
        float ay = __uint_as_float((u32)a.y << 16), cy = __uint_as_float((u32)c.y << 16);
        float az = __uint_as_float((u32)a.z << 16), cz = __uint_as_float((u32)c.z << 16);
        float aw = __uint_as_float((u32)a.w << 16), cw = __uint_as_float((u32)c.w << 16);
        float dx = ax - cx + 1e-8f;
        float dy = ay - cy + 1e-8f;
        float dz = az - cz + 1e-8f;
        float dw = aw - cw + 1e-8f;
        float sum = dx * dx + dy * dy + dz * dz + dw * dw;
#pragma unroll
        for (int m = 32; m >= 1; m >>= 1)
            sum += __shfl_xor(sum, m, 64);
        if (lane == 0)
            lsum += logf(sqrtf(sum) + 1e-8f);
    }

    __shared__ float red[4];
    if (lane == 0) red[wave] = lsum;
    __syncthreads();
    if (threadIdx.x == 0) {
        float s = red[0] + red[1] + red[2] + red[3];
        atomicAdd(out, -s * (1.0f / (Bq * Tq)));
    }
}

extern "C" void kernel_launch(void* const* d_in, const int* in_sizes, int n_in,
                              void* d_out, int out_size, void* d_ws, size_t ws_size,
                              hipStream_t stream) {
    const float* x = (const float*)d_in[0];
    float* out = (float*)d_out;

    unsigned short* xb = (unsigned short*)d_ws;                        // 16 MB bf16 copy
    u64* keys = (u64*)((char*)d_ws + (size_t)Bq * Tq * Dq * 2);        // 256 KB keys

    hipMemsetAsync(d_out, 0, sizeof(float), stream);
    hipMemsetAsync(keys, 0, (size_t)Bq * Tq * sizeof(u64), stream);    // key=0 < any real

    const int n4 = Bq * Tq * Dq / 4;
    cvt_kernel<<<n4 / 256, 256, 0, stream>>>(x, xb);
    argmax_kernel<<<Bq * NPAIR, 512, 0, stream>>>(xb, keys);
    loss_kernel<<<512, 256, 0, stream>>>(xb, keys, out);
}

// Round 10
// 104.253 us; speedup vs baseline: 1.6149x; 1.6149x over previous
//
#include <hip/hip_runtime.h>
#include <hip/hip_bf16.h>
#include <math.h>

// KoLeo loss: B=8, T=4096, D=256 fp32 input.
// Phase 1: convert x -> bf16 (ws)
// Phase 2: per-batch Gram X·X^T via bf16 MFMA; A (256 rows) register-resident,
//          B staged via global_load_lds (swizzled, 2x32KB dbuf) and streamed
//          over s (R3 structure -- measured best across R3..R9);
//          streaming per-row argmax merged across s-halves with atomicMax
//          on packed (orderable-f32, ~idx) u64 keys.
// Phase 3: bf16 distances (from xb, L2-hot) + log-mean loss.

#define Bq 8
#define Tq 4096
#define Dq 256
#define SBLK 64          // s-columns staged per tile
#define NST 32           // tiles per s-half: 2048 / 64
#define S_HALF 2048

typedef __attribute__((ext_vector_type(8))) short bf16x8;
typedef __attribute__((ext_vector_type(4))) float f32x4;
typedef unsigned int u32;
typedef unsigned long long u64;

__device__ __forceinline__ unsigned short f2bf(float f) {
    unsigned int u = __float_as_uint(f);
    unsigned int r = (u + 0x7fffu + ((u >> 16) & 1u)) >> 16;   // RNE
    return (unsigned short)r;
}

__device__ __forceinline__ void gload_lds16(const void* g, void* l) {
    typedef __attribute__((address_space(1))) const unsigned int gu32;
    typedef __attribute__((address_space(3))) unsigned int lu32;
    __builtin_amdgcn_global_load_lds((gu32*)g, (lu32*)l, 16, 0, 0);
}

// ---------------- Phase 1: fp32 -> bf16 ----------------
__global__ void cvt_kernel(const float* __restrict__ x, unsigned short* __restrict__ xb) {
    int i = blockIdx.x * blockDim.x + threadIdx.x;  // one float4 per thread
    const int n4 = Bq * Tq * Dq / 4;
    if (i < n4) {
        float4 v = ((const float4*)x)[i];
        ushort4 o;
        o.x = f2bf(v.x); o.y = f2bf(v.y); o.z = f2bf(v.z); o.w = f2bf(v.w);
        ((ushort4*)xb)[i] = o;
    }
}

// ---------------- Phase 2: Gram + streaming argmax (R3 structure) ----------------
// Grid: 256 blocks = 8 batches x 16 row-tiles(256 rows) x 2 s-halves(2048 cols).
//   batch = bid & 7 -> same-batch blocks share an XCD L2 (2 MB panel resident).
// Block: 512 threads = 8 waves as 4M x 2N. Wave tile: 64 rows (mi=4) x 32 cols (ni=2).
// B: LDS double-buffer 2 x 64 x 512 B = 64 KB, staged with global_load_lds width=16,
//    XOR-swizzled (linear LDS dest + pre-swizzled global src + swizzled ds_read).
// Plateau notes (measured): occupancy pinned at 2 waves/SIMD by unified VGPR+AGPR
//   (~220/wave); counted-vmcnt/triple-buffer (R6), reg pinning (R7), barrier
//   halving (R8), symmetry split (R9) all null or negative vs this structure.
// NOTE: launch_bounds must stay (512,2); (512,4) demotes afrag -> 870 MB FETCH (R4).
__global__ __launch_bounds__(512, 2)
void argmax_kernel(const unsigned short* __restrict__ xb, u64* __restrict__ keys) {
    const int bid   = blockIdx.x;
    const int batch = bid & 7;
    const int rt    = (bid >> 3) & 15;     // row-tile 0..15 (256 rows each)
    const int sh    = bid >> 7;            // s-half 0..1
    const int tid   = threadIdx.x;
    const int lane  = tid & 63;
    const int wave  = tid >> 6;            // 0..7
    const int waveM = wave >> 1;           // 0..3
    const int waveN = wave & 1;            // 0..1
    const int lrow  = lane & 15;           // A-row / B-col / C-col
    const int lk    = lane >> 4;           // k-group / C row-group

    const unsigned short* xB = xb + (size_t)batch * Tq * Dq;
    const char* xBb = (const char*)xB;                 // byte view, row stride 512 B
    const int rowBase = rt * 256 + waveM * 64;         // wave's 64 rows
    const int sHalfBase = sh * S_HALF;

    __shared__ char smem[2 * SBLK * 512];              // 64 KB double buffer

    // ---- A fragments: afrag[kk][mi] ----
    bf16x8 afrag[8][4];
#pragma unroll
    for (int mi = 0; mi < 4; ++mi) {
        const unsigned short* rp = xB + (size_t)(rowBase + mi * 16 + lrow) * Dq + lk * 8;
#pragma unroll
        for (int kk = 0; kk < 8; ++kk)
            afrag[kk][mi] = *(const bf16x8*)(rp + kk * 32);
    }

    // ---- staging: tile st (64 s-rows x 512 B) into buffer buf ----
    // LDS linear slot ls = s_local*512 + q holds global byte (q ^ ((s_local&7)<<4))
    // of row (S0 + s_local): linear dest + inverse-swizzled source (rule #21).
    auto STAGE = [&](int st, int buf) {
        const int S0 = sHalfBase + st * SBLK;
        char* lbase = smem + buf * (SBLK * 512);
#pragma unroll
        for (int it = 0; it < 4; ++it) {
            const int ls = it * 8192 + tid * 16;       // 0..32767, wave-contiguous
            const int s_local = ls >> 9;
            const int q = ls & 511;
            const char* g = xBb + (size_t)(S0 + s_local) * 512 + (q ^ ((s_local & 7) << 4));
            gload_lds16(g, lbase + ls);
        }
    };

    float best[4][4];   // [mi][j]
    int   bidxv[4][4];
#pragma unroll
    for (int mi = 0; mi < 4; ++mi)
#pragma unroll
        for (int j = 0; j < 4; ++j) { best[mi][j] = -1e30f; bidxv[mi][j] = 0; }

    STAGE(0, 0);
    asm volatile("s_waitcnt vmcnt(0)");
    __syncthreads();

    for (int st = 0; st < NST; ++st) {
        const int buf = st & 1;
        if (st + 1 < NST) STAGE(st + 1, buf ^ 1);

        const char* lbase = smem + buf * (SBLK * 512);
        const int S0 = sHalfBase + st * SBLK;
        const int sW = waveN * 32;                     // wave's local col base

        f32x4 acc[4][2];
#pragma unroll
        for (int mi = 0; mi < 4; ++mi)
#pragma unroll
            for (int ni = 0; ni < 2; ++ni)
                acc[mi][ni] = (f32x4){0.f, 0.f, 0.f, 0.f};

#pragma unroll
        for (int kk = 0; kk < 8; ++kk) {
            bf16x8 bfr[2];
#pragma unroll
            for (int ni = 0; ni < 2; ++ni) {
                const int s_local = sW + ni * 16 + lrow;
                bfr[ni] = *(const bf16x8*)(lbase + s_local * 512 +
                                           ((kk * 64 + lk * 16) ^ ((s_local & 7) << 4)));
            }
#pragma unroll
            for (int mi = 0; mi < 4; ++mi)
#pragma unroll
                for (int ni = 0; ni < 2; ++ni)
                    acc[mi][ni] = __builtin_amdgcn_mfma_f32_16x16x32_bf16(
                        afrag[kk][mi], bfr[ni], acc[mi][ni], 0, 0, 0);
        }

        // streaming argmax update (diag always guarded; strict '>' + ascending s)
#pragma unroll
        for (int mi = 0; mi < 4; ++mi) {
            const int tbase = rowBase + mi * 16 + lk * 4;
#pragma unroll
            for (int j = 0; j < 4; ++j) {
                const int tj = tbase + j;
#pragma unroll
                for (int ni = 0; ni < 2; ++ni) {
                    const float v = acc[mi][ni][j];
                    const int s = S0 + sW + ni * 16 + lrow;
                    const bool ok = (s != tj) && (v > best[mi][j]);
                    best[mi][j] = ok ? v : best[mi][j];
                    bidxv[mi][j] = ok ? s : bidxv[mi][j];
                }
            }
        }

        asm volatile("s_waitcnt vmcnt(0)");
        __syncthreads();
    }

    // ---- reduce across the 16 lanes sharing each C-row, then global atomicMax ----
#pragma unroll
    for (int mi = 0; mi < 4; ++mi) {
#pragma unroll
        for (int j = 0; j < 4; ++j) {
            float v = best[mi][j];
            int   ix = bidxv[mi][j];
#pragma unroll
            for (int m = 8; m >= 1; m >>= 1) {
                float ov = __shfl_xor(v, m, 64);
                int   oi = __shfl_xor(ix, m, 64);
                if (ov > v || (ov == v && oi < ix)) { v = ov; ix = oi; }
            }
            if (lrow == 0) {
                const int row = rowBase + mi * 16 + lk * 4 + j;
                const u32 u = __float_as_uint(v);
                const u32 o = (u & 0x80000000u) ? ~u : (u | 0x80000000u);  // orderable
                const u64 key = ((u64)o << 32) | (u32)(~ix);               // ties: low idx
                atomicMax(keys + batch * Tq + row, key);
            }
        }
    }
}

// ---------------- Phase 3: bf16 distance + loss ----------------
// Distances from the bf16 copy (L2/L3-hot, half the bytes of fp32 x).
// Error: per-element ~0.4% rel -> log error ~2e-4, far under the 0.06 threshold.
__global__ void loss_kernel(const unsigned short* __restrict__ xb,
                            const u64* __restrict__ keys, float* __restrict__ out) {
    const int lane = threadIdx.x & 63;
    const int wave = threadIdx.x >> 6;          // 4 waves / block
    const int gw = blockIdx.x * 4 + wave;       // 2048 global waves
    float lsum = 0.f;

    for (int row = gw; row < Bq * Tq; row += 2048) {
        const int b = row >> 12;
        const int t = row & (Tq - 1);
        const int s = (int)((u32)(~keys[row]));
        const ushort4* xt = (const ushort4*)(xb + ((size_t)b * Tq + t) * Dq);
        const ushort4* xs = (const ushort4*)(xb + ((size_t)b * Tq + s) * Dq);
        ushort4 a = xt[lane];                   // 4 bf16 per lane, 64 lanes = 256
        ushort4 c = xs[lane];
        float ax = __uint_as_float((u32)a.x << 16), cx = __uint_as_float((u32)c.x << 16);
        float ay = __uint_as_float((u32)a.y << 16), cy = __uint_as_float((u32)c.y << 16);
        float az = __uint_as_float((u32)a.z << 16), cz = __uint_as_float((u32)c.z << 16);
        float aw = __uint_as_float((u32)a.w << 16), cw = __uint_as_float((u32)c.w << 16);
        float dx = ax - cx + 1e-8f;
        float dy = ay - cy + 1e-8f;
        float dz = az - cz + 1e-8f;
        float dw = aw - cw + 1e-8f;
        float sum = dx * dx + dy * dy + dz * dz + dw * dw;
#pragma unroll
        for (int m = 32; m >= 1; m >>= 1)
            sum += __shfl_xor(sum, m, 64);
        if (lane == 0)
            lsum += logf(sqrtf(sum) + 1e-8f);
    }

    __shared__ float red[4];
    if (lane == 0) red[wave] = lsum;
    __syncthreads();
    if (threadIdx.x == 0) {
        float s = red[0] + red[1] + red[2] + red[3];
        atomicAdd(out, -s * (1.0f / (Bq * Tq)));
    }
}

extern "C" void kernel_launch(void* const* d_in, const int* in_sizes, int n_in,
                              void* d_out, int out_size, void* d_ws, size_t ws_size,
                              hipStream_t stream) {
    const float* x = (const float*)d_in[0];
    float* out = (float*)d_out;

    unsigned short* xb = (unsigned short*)d_ws;                        // 16 MB bf16 copy
    u64* keys = (u64*)((char*)d_ws + (size_t)Bq * Tq * Dq * 2);        // 256 KB keys

    hipMemsetAsync(d_out, 0, sizeof(float), stream);
    hipMemsetAsync(keys, 0, (size_t)Bq * Tq * sizeof(u64), stream);    // key=0 < any real

    const int n4 = Bq * Tq * Dq / 4;
    cvt_kernel<<<n4 / 256, 256, 0, stream>>>(x, xb);
    argmax_kernel<<<256, 512, 0, stream>>>(xb, keys);
    loss_kernel<<<512, 256, 0, stream>>>(xb, keys, out);
}